// Round 16
// baseline (89.748 us; speedup 1.0000x reference)
//
#include <hip/hip_runtime.h>
#include <hip/hip_bf16.h>

typedef __bf16 bf16x8 __attribute__((ext_vector_type(8)));
typedef float f32x4 __attribute__((ext_vector_type(4)));
typedef ushort us8 __attribute__((ext_vector_type(8)));

#define MFMA(a, b, c) __builtin_amdgcn_mfma_f32_16x16x32_bf16((a), (b), (c), 0, 0, 0)

static constexpr int T_LEN = 2048;
static constexpr int C_DIM = 1024;
static constexpr int H_DIM = 128;
static constexpr int M_ROWS = 8 * 2048;    // 16384
static constexpr int N_COLS = 384;         // 3 * 128
static constexpr int SLOTS_PER_B = 528;    // partial slots (qi>=32)
static constexpr int PSTR = 72;            // P buffer row stride
static constexpr int KSTR = 136;           // K LDS row stride (272B, 2-way max)
static constexpr int VSTR = 72;            // V LDS row stride (144B, 2-way max)

__device__ __forceinline__ ushort f2bf(float f) {
  union { float f; unsigned u; } v; v.f = f;
  unsigned u = v.u;
  u += 0x7fffu + ((u >> 16) & 1u);
  return (ushort)(u >> 16);
}
__device__ __forceinline__ float bf2f(ushort u) {
  union { unsigned u; float f; } v; v.u = (unsigned)u << 16;
  return v.f;
}

// async global->LDS: 16B per lane, LDS dest = wave-uniform base + lane*16.
__device__ __forceinline__ void gl2lds16(const ushort* g, ushort* l) {
  __builtin_amdgcn_global_load_lds(
      (const __attribute__((address_space(1))) unsigned int*)(const void*)g,
      (__attribute__((address_space(3))) unsigned int*)(void*)l, 16, 0, 0);
}

// ---------------------------------------------------------------------------
// Kernel 0: Wq/Wk/Wv fp32 [1024][128] -> bf16 wt_frag, MFMA-FRAGMENT layout:
//   wt[((kt*24 + cg)*64 + lane)*8 + j] = W(c = kt*32 + (lane>>4)*8 + j,
//                                          gc = cg*16 + (lane&15))
// ---------------------------------------------------------------------------
__global__ void wt_convert(const float* __restrict__ Wq,
                           const float* __restrict__ Wk,
                           const float* __restrict__ Wv,
                           ushort* __restrict__ wt) {
  int o = blockIdx.x * 256 + threadIdx.x;   // 0..393215
  int kt = o / 12288;                        // 24 cg * 64 lanes * 8 elems
  int rem = o - kt * 12288;
  int cg = rem >> 9;
  int lane = (rem >> 3) & 63;
  int j = rem & 7;
  int gc = cg * 16 + (lane & 15);
  int c  = kt * 32 + (lane >> 4) * 8 + j;
  int mat = gc >> 7;
  int h   = gc & 127;
  const float* W = (mat == 0) ? Wq : ((mat == 1) ? Wk : Wv);
  wt[o] = f2bf(W[c * H_DIM + h]);
}

// ---------------------------------------------------------------------------
// Kernel 1: fused QKV projection v6 — m97-style global_load_lds staging.
//  - B: 3x global_load_lds(16B)/thread into linear LDS [12cg][64lane][16B]
//    (wt_frag order == LDS order; both sides lane-contiguous, no swizzle).
//  - A: reg->LDS bf16 [32][32] linear (full-coverage, conflict-free).
//  - BM=32, BN=192, BK=32 -> 1024 blocks, 4/CU, 16 waves/CU; ONE
//    __syncthreads per iter (2-phase T3-minimum); cross-block overlap
//    hides the barrier drain (m114/m97).
// ---------------------------------------------------------------------------
__global__ __launch_bounds__(256, 4) void qkv_gemm(const float* __restrict__ X,
                                                   const ushort* __restrict__ wt,
                                                   ushort* __restrict__ qws,
                                                   ushort* __restrict__ kws,
                                                   ushort* __restrict__ vtws) {
  __shared__ ushort As[2][32 * 32];    // 2 KB each
  __shared__ ushort Bs[2][12 * 512];   // 12 KB each
  const int tid = threadIdx.x;
  const int wid = tid >> 6, lane = tid & 63;
  const int lg = lane >> 4, lr = lane & 15;
  const int m0 = (blockIdx.x >> 1) * 32;
  const int n0 = (blockIdx.x & 1) * 192;
  const float QSCL = 0.03125f * 1.44269504f;

  // A staging: thread -> row tid>>3, 4 cols at (tid&7)*4
  const int arow = tid >> 3;
  const float* gA = &X[(size_t)(m0 + arow) * C_DIM + (tid & 7) * 4];
  const int aws = arow * 32 + (tid & 7) * 4;          // ushort idx in As

  // B staging: per-kt global base (ushort idx); wave handles chunks wid, wid+4, wid+8
  const size_t wtb0 = (size_t)((blockIdx.x & 1) * 12) * 512 + (size_t)wid * 512 + (size_t)lane * 8;

  // fragment read bases
  const int afb = lr * 32 + lg * 8;                   // ushort idx; a1 at +512

  f32x4 acc[2][3];
#pragma unroll
  for (int r = 0; r < 2; ++r)
#pragma unroll
    for (int c = 0; c < 3; ++c)
      acc[r][c] = f32x4{0.f, 0.f, 0.f, 0.f};

  // ---- prologue: stage tile 0 ----
  {
    float4 x = *(const float4*)gA;
    ushort4 av;
    av.x = f2bf(x.x); av.y = f2bf(x.y); av.z = f2bf(x.z); av.w = f2bf(x.w);
    *(ushort4*)&As[0][aws] = av;
    const ushort* gB = wt + wtb0;                     // kt = 0
    gl2lds16(gB,        &Bs[0][(size_t)wid * 512]);
    gl2lds16(gB + 2048, &Bs[0][(size_t)(4 + wid) * 512]);
    gl2lds16(gB + 4096, &Bs[0][(size_t)(8 + wid) * 512]);
  }
  __syncthreads();

  int cur = 0;
  for (int kt = 0; kt < 32; ++kt) {
    // issue next tile's staging first (latency hides under this iter's compute)
    float4 an;
    if (kt + 1 < 32) {
      an = *(const float4*)(gA + (kt + 1) * 32);
      const ushort* gBn = wt + (size_t)(kt + 1) * 12288 + wtb0;
      gl2lds16(gBn,        &Bs[cur ^ 1][(size_t)wid * 512]);
      gl2lds16(gBn + 2048, &Bs[cur ^ 1][(size_t)(4 + wid) * 512]);
      gl2lds16(gBn + 4096, &Bs[cur ^ 1][(size_t)(8 + wid) * 512]);
    }

    // compute from current buffers
    bf16x8 a0 = *(const bf16x8*)&As[cur][afb];
    bf16x8 a1 = *(const bf16x8*)&As[cur][afb + 512];
#pragma unroll
    for (int c = 0; c < 3; ++c) {
      bf16x8 bf = *(const bf16x8*)&Bs[cur][(size_t)(wid * 3 + c) * 512 + (size_t)lane * 8];
      acc[0][c] = MFMA(a0, bf, acc[0][c]);
      acc[1][c] = MFMA(a1, bf, acc[1][c]);
    }

    // write next A tile (regs loaded this iter) into the other buffer
    if (kt + 1 < 32) {
      ushort4 av;
      av.x = f2bf(an.x); av.y = f2bf(an.y); av.z = f2bf(an.z); av.w = f2bf(an.w);
      *(ushort4*)&As[cur ^ 1][aws] = av;
    }
    __syncthreads();   // drains vmcnt (gloads done) + lgkmcnt; publishes buf^1
    cur ^= 1;
  }

  // epilogue: C frag layout col=lane&15, row=(lane>>4)*4+j
#pragma unroll
  for (int c = 0; c < 3; ++c) {
    int gc = n0 + wid * 48 + c * 16 + lr;
    int mat = gc >> 7, h = gc & 127;
#pragma unroll
    for (int r = 0; r < 2; ++r) {
#pragma unroll
      for (int j = 0; j < 4; ++j) {
        int gr = m0 + r * 16 + lg * 4 + j;
        float val = acc[r][c][j];
        ushort ov = f2bf(mat == 0 ? val * QSCL : val);
        if (mat == 0) {
          qws[(size_t)gr * H_DIM + h] = ov;
        } else if (mat == 1) {
          kws[(size_t)gr * H_DIM + h] = ov;
        } else {
          int b = gr >> 11, t = gr & 2047;
          vtws[((size_t)b * H_DIM + h) * T_LEN + t] = ov;
        }
      }
    }
  }
}

// ---------------------------------------------------------------------------
// Kernel 2a: flash partial pass, block-cooperative LDS-staged K/V
// (unchanged from round 9).
// ---------------------------------------------------------------------------
__global__ __launch_bounds__(256, 3) void attn_part(const ushort* __restrict__ qws,
                                                    const ushort* __restrict__ kws,
                                                    const ushort* __restrict__ vtws,
                                                    float* __restrict__ pml,
                                                    ushort* __restrict__ pacc,
                                                    float* __restrict__ out) {
  __shared__ ushort Klds[64 * KSTR];
  __shared__ ushort Vlds[128 * VSTR];
  __shared__ ushort Pw[4][16 * PSTR];

  const int tid = threadIdx.x;
  const int wid = tid >> 6, lane = tid & 63;
  const int lg = lane >> 4, lr = lane & 15;
  const int bid = blockIdx.x;
  const int b = bid & 7;
  const int item = bid >> 3;

  int qb, ck;
  bool direct;
  if (item < 8) {
    qb = item; ck = 0; direct = true;
  } else {
    const int p = item - 8;
    direct = false;
    if (p < 12)      { int q = p / 3;        qb = 8 + q;  ck = p - q * 3; }
    else if (p < 28) { int q = (p - 12) >> 2; qb = 12 + q; ck = (p - 12) & 3; }
    else if (p < 48) { int q = (p - 28) / 5; qb = 16 + q; ck = (p - 28) - q * 5; }
    else if (p < 72) { int q = (p - 48) / 6; qb = 20 + q; ck = (p - 48) - q * 6; }
    else if (p < 100){ int q = (p - 72) / 7; qb = 24 + q; ck = (p - 72) - q * 7; }
    else             { int q = (p - 100) >> 3; qb = 28 + q; ck = (p - 100) & 7; }
  }
  const int qi = qb * 4 + wid;
  const int q0 = qi * 16;
  const int nt = qb + 1;
  const int kvt_lo = direct ? 0 : ck * 4;
  const int kvt_hi = direct ? nt : min(ck * 4 + 4, nt);
  const size_t tokbase = (size_t)b * T_LEN;
  const ushort* vb = vtws + (size_t)b * H_DIM * T_LEN;

  const int kr = tid >> 2, kseg = tid & 3;
  const int vr = tid >> 1, vseg = tid & 1;
  const ushort* gK = &kws[(tokbase + kr) * H_DIM + kseg * 32];
  const ushort* gV = &vb[(size_t)vr * T_LEN + vseg * 32];

  bf16x8 qf[4];
#pragma unroll
  for (int hk = 0; hk < 4; ++hk)
    qf[hk] = *(const bf16x8*)&qws[(tokbase + q0 + lr) * H_DIM + hk * 32 + lg * 8];

  f32x4 acc[8];
#pragma unroll
  for (int hf = 0; hf < 8; ++hf) acc[hf] = f32x4{0.f, 0.f, 0.f, 0.f};
  float mrun = -INFINITY, lrun = 0.f;

  ushort* Pme = &Pw[wid][0];

  us8 kreg[4], vreg[4];
#pragma unroll
  for (int i = 0; i < 4; ++i) {
    kreg[i] = *(const us8*)(gK + (size_t)kvt_lo * 64 * H_DIM + i * 8);
    vreg[i] = *(const us8*)(gV + kvt_lo * 64 + i * 8);
  }

  for (int kvt = kvt_lo; kvt < kvt_hi; ++kvt) {
    const int kv0 = kvt * 64;

    __syncthreads();
#pragma unroll
    for (int i = 0; i < 4; ++i) {
      *(us8*)&Klds[kr * KSTR + kseg * 32 + i * 8] = kreg[i];
      *(us8*)&Vlds[vr * VSTR + vseg * 32 + i * 8] = vreg[i];
    }
    if (kvt + 1 < kvt_hi) {
#pragma unroll
      for (int i = 0; i < 4; ++i) {
        kreg[i] = *(const us8*)(gK + (size_t)(kv0 + 64) * H_DIM + i * 8);
        vreg[i] = *(const us8*)(gV + kv0 + 64 + i * 8);
      }
    }
    __syncthreads();

    f32x4 s[4];
#pragma unroll
    for (int c = 0; c < 4; ++c) {
      f32x4 sc = f32x4{0.f, 0.f, 0.f, 0.f};
#pragma unroll
      for (int hk = 0; hk < 4; ++hk) {
        bf16x8 kf = *(const bf16x8*)&Klds[(c * 16 + lr) * KSTR + hk * 32 + lg * 8];
        sc = MFMA(kf, qf[hk], sc);
      }
      s[c] = sc;
    }

    if (kvt == nt - 1) {
#pragma unroll
      for (int c = 0; c < 4; ++c)
#pragma unroll
        for (int j = 0; j < 4; ++j) {
          int kv = kv0 + c * 16 + lg * 4 + j;
          if (kv > q0 + lr) s[c][j] = -INFINITY;
        }
    }

    float mx = s[0][0];
#pragma unroll
    for (int c = 0; c < 4; ++c)
#pragma unroll
      for (int j = 0; j < 4; ++j) mx = fmaxf(mx, s[c][j]);
    mx = fmaxf(mx, __shfl_xor(mx, 16));
    mx = fmaxf(mx, __shfl_xor(mx, 32));

    float mnew = fmaxf(mrun, mx);
    float scold = exp2f(mrun - mnew);

    float rsum = 0.f;
#pragma unroll
    for (int c = 0; c < 4; ++c)
#pragma unroll
      for (int j = 0; j < 4; ++j) {
        float p = exp2f(s[c][j] - mnew);
        s[c][j] = p;
        rsum += p;
      }

#pragma unroll
    for (int c = 0; c < 4; ++c) {
      ushort4 u;
      u.x = f2bf(s[c][0]); u.y = f2bf(s[c][1]);
      u.z = f2bf(s[c][2]); u.w = f2bf(s[c][3]);
      *(ushort4*)&Pme[lr * PSTR + c * 16 + lg * 4] = u;
    }

    bf16x8 v0[8];
#pragma unroll
    for (int hf = 0; hf < 8; ++hf)
      v0[hf] = *(const bf16x8*)&Vlds[(hf * 16 + lr) * VSTR + lg * 8];

    rsum += __shfl_xor(rsum, 16);
    rsum += __shfl_xor(rsum, 32);

    lrun = lrun * scold + rsum;
    mrun = mnew;
#pragma unroll
    for (int hf = 0; hf < 8; ++hf)
#pragma unroll
      for (int j = 0; j < 4; ++j) acc[hf][j] *= scold;

    bf16x8 pa0 = *(const bf16x8*)&Pme[lr * PSTR + lg * 8];
    bf16x8 pa1 = *(const bf16x8*)&Pme[lr * PSTR + 32 + lg * 8];

#pragma unroll
    for (int hf = 0; hf < 8; ++hf)
      acc[hf] = MFMA(v0[hf], pa0, acc[hf]);
#pragma unroll
    for (int hf = 0; hf < 8; ++hf) {
      bf16x8 v1 = *(const bf16x8*)&Vlds[(hf * 16 + lr) * VSTR + 32 + lg * 8];
      acc[hf] = MFMA(v1, pa1, acc[hf]);
    }
  }

  if (direct) {
    float inv = 1.0f / lrun;
    float* op = &out[(tokbase + q0 + lr) * H_DIM + lg * 4];
#pragma unroll
    for (int hf = 0; hf < 8; ++hf) {
      float4 r0 = make_float4(acc[hf][0] * inv, acc[hf][1] * inv,
                              acc[hf][2] * inv, acc[hf][3] * inv);
      *(float4*)(op + hf * 16) = r0;
    }
  } else {
    int base;
    if (qi < 48)       base = (qi - 32) * 3;
    else if (qi < 64)  base = 48 + (qi - 48) * 4;
    else if (qi < 80)  base = 112 + (qi - 64) * 5;
    else if (qi < 96)  base = 192 + (qi - 80) * 6;
    else if (qi < 112) base = 288 + (qi - 96) * 7;
    else               base = 400 + (qi - 112) * 8;
    const size_t slot = (size_t)b * SLOTS_PER_B + base + ck;
    if (lg == 0) {
      pml[slot * 32 + lr] = mrun;
      pml[slot * 32 + 16 + lr] = lrun;
    }
    ushort* ap = &pacc[slot * 2048 + (size_t)lr * 128 + lg * 4];
#pragma unroll
    for (int hf = 0; hf < 8; ++hf) {
      ushort4 u;
      u.x = f2bf(acc[hf][0]); u.y = f2bf(acc[hf][1]);
      u.z = f2bf(acc[hf][2]); u.w = f2bf(acc[hf][3]);
      *(ushort4*)(ap + hf * 16) = u;
    }
  }
}

// ---------------------------------------------------------------------------
// Kernel 2b: online merge of 3..8 partials per (b, qi) for qi >= 32.
// (unchanged)
// ---------------------------------------------------------------------------
__global__ __launch_bounds__(256) void attn_merge(const float* __restrict__ pml,
                                                  const ushort* __restrict__ pacc,
                                                  float* __restrict__ out) {
  const int bid = blockIdx.x;
  const int b = bid & 7, qi = (bid >> 3) + 32;
  int base, nch;
  if (qi < 48)       { base = (qi - 32) * 3;        nch = 3; }
  else if (qi < 64)  { base = 48 + (qi - 48) * 4;   nch = 4; }
  else if (qi < 80)  { base = 112 + (qi - 64) * 5;  nch = 5; }
  else if (qi < 96)  { base = 192 + (qi - 80) * 6;  nch = 6; }
  else if (qi < 112) { base = 288 + (qi - 96) * 7;  nch = 7; }
  else               { base = 400 + (qi - 112) * 8; nch = 8; }
  const size_t slot0 = (size_t)b * SLOTS_PER_B + base;
  const int tid = threadIdx.x;
  const int r = tid >> 4, c0 = (tid & 15) * 8;

  float mrun = -INFINITY, L = 0.f;
  float o[8];
#pragma unroll
  for (int i = 0; i < 8; ++i) o[i] = 0.f;

  for (int ck = 0; ck < nch; ++ck) {
    const size_t s = slot0 + ck;
    float m = pml[s * 32 + r];
    float l = pml[s * 32 + 16 + r];
    float mn = fmaxf(mrun, m);
    float sc = exp2f(mrun - mn);
    float w  = exp2f(m - mn);
    L = L * sc + w * l;
    const ushort* ap = &pacc[s * 2048 + (size_t)r * 128 + c0];
    ushort4 u0 = *(const ushort4*)ap;
    ushort4 u1 = *(const ushort4*)(ap + 4);
    o[0] = o[0] * sc + w * bf2f(u0.x); o[1] = o[1] * sc + w * bf2f(u0.y);
    o[2] = o[2] * sc + w * bf2f(u0.z); o[3] = o[3] * sc + w * bf2f(u0.w);
    o[4] = o[4] * sc + w * bf2f(u1.x); o[5] = o[5] * sc + w * bf2f(u1.y);
    o[6] = o[6] * sc + w * bf2f(u1.z); o[7] = o[7] * sc + w * bf2f(u1.w);
    mrun = mn;
  }
  float invL = 1.0f / L;
  float4 r0 = make_float4(o[0] * invL, o[1] * invL, o[2] * invL, o[3] * invL);
  float4 r1 = make_float4(o[4] * invL, o[5] * invL, o[6] * invL, o[7] * invL);
  float* op = &out[((size_t)b * T_LEN + qi * 16 + r) * H_DIM + c0];
  *(float4*)op = r0;
  *(float4*)(op + 4) = r1;
}

// ---------------------------------------------------------------------------
// ws layout identical to rounds 8-15 (total 30,670,848 B, proven fit):
//   [0, 786432) wt_frag (dead after qkv_gemm; pml overlaps, 540,672 B)
//   qws / kws / vtws ; pacc = 8*528 slots * 2048 bf16
// ---------------------------------------------------------------------------
extern "C" void kernel_launch(void* const* d_in, const int* in_sizes, int n_in,
                              void* d_out, int out_size, void* d_ws, size_t ws_size,
                              hipStream_t stream) {
  const float* emb = (const float*)d_in[0];
  const float* Wq  = (const float*)d_in[1];
  const float* Wk  = (const float*)d_in[2];
  const float* Wv  = (const float*)d_in[3];
  float* out = (float*)d_out;

  ushort* wt   = (ushort*)d_ws;
  ushort* qws  = wt  + (size_t)N_COLS * C_DIM;
  ushort* kws  = qws + (size_t)M_ROWS * H_DIM;
  ushort* vtws = kws + (size_t)M_ROWS * H_DIM;
  ushort* pacc = vtws + (size_t)8 * H_DIM * T_LEN;
  float*  pml  = (float*)d_ws;   // overlaps dead wt region

  wt_convert<<<(N_COLS * C_DIM) / 256, 256, 0, stream>>>(Wq, Wk, Wv, wt);
  qkv_gemm<<<(M_ROWS / 32) * 2, 256, 0, stream>>>(emb, wt, qws, kws, vtws);
  attn_part<<<8 * 140, 256, 0, stream>>>(qws, kws, vtws, pml, pacc, out);
  attn_merge<<<8 * 96, 256, 0, stream>>>(pml, pacc, out);
}

// Round 17
// 79.471 us; speedup vs baseline: 1.1293x; 1.1293x over previous
//
#include <hip/hip_runtime.h>
#include <hip/hip_bf16.h>

typedef __bf16 bf16x8 __attribute__((ext_vector_type(8)));
typedef float f32x4 __attribute__((ext_vector_type(4)));
typedef ushort us8 __attribute__((ext_vector_type(8)));

#define MFMA(a, b, c) __builtin_amdgcn_mfma_f32_16x16x32_bf16((a), (b), (c), 0, 0, 0)

static constexpr int T_LEN = 2048;
static constexpr int C_DIM = 1024;
static constexpr int H_DIM = 128;
static constexpr int M_ROWS = 8 * 2048;    // 16384
static constexpr int N_COLS = 384;         // 3 * 128
static constexpr int SLOTS_PER_B = 528;    // partial slots (qi>=32)
static constexpr int PSTR = 72;            // P buffer row stride
static constexpr int KSTR = 136;           // K LDS row stride (272B, 2-way max)
static constexpr int VSTR = 72;            // V LDS row stride (144B, 2-way max)

__device__ __forceinline__ ushort f2bf(float f) {
  union { float f; unsigned u; } v; v.f = f;
  unsigned u = v.u;
  u += 0x7fffu + ((u >> 16) & 1u);
  return (ushort)(u >> 16);
}
__device__ __forceinline__ float bf2f(ushort u) {
  union { unsigned u; float f; } v; v.u = (unsigned)u << 16;
  return v.f;
}

// raw barrier: lgkmcnt(0) for LDS visibility, NO vmcnt drain.
__device__ __forceinline__ void waitbar() {
  asm volatile("s_waitcnt lgkmcnt(0)" ::: "memory");
  __builtin_amdgcn_s_barrier();
  __builtin_amdgcn_sched_barrier(0);
}

// G4-standard swizzle for 128B rows ([R][64] bf16): row r, 16B-slot s (0..7):
//   byte = r*128 + ((s*16) ^ ((r&7)<<4))
// Frag reads (16 lanes, rows r0..r0+15, fixed s): XOR spreads 8 consecutive
// rows over all 8 slot positions -> every 16B bank-span hit exactly 2x (free).
// Stage writes cover full rows -> conflict-free by construction.
__device__ __forceinline__ int sw128(int row, int slot) {
  return row * 128 + ((slot * 16) ^ ((row & 7) << 4));
}

// ---------------------------------------------------------------------------
// Kernel 0: Wq/Wk/Wv fp32 [1024][128] -> bf16 wt_t, BK=64 K-STEP-TILED:
//   wt_t[(kt*384 + gc)*64 + kk] = W(c = kt*64+kk, gc)   kt=0..15
// Each K-step's 192-col B-tile is a contiguous 24 KB block.
// ---------------------------------------------------------------------------
__global__ void wt_convert(const float* __restrict__ Wq,
                           const float* __restrict__ Wk,
                           const float* __restrict__ Wv,
                           ushort* __restrict__ wt) {
  int o = blockIdx.x * 256 + threadIdx.x;   // 0..393215
  int kt = o / 24576;                        // 384*64
  int rem = o - kt * 24576;
  int gc = rem >> 6;
  int kk = rem & 63;
  int c  = kt * 64 + kk;
  int mat = gc >> 7;
  int h   = gc & 127;
  const float* W = (mat == 0) ? Wq : ((mat == 1) ? Wk : Wv);
  wt[o] = f2bf(W[c * H_DIM + h]);
}

// ---------------------------------------------------------------------------
// Kernel 1: fused QKV projection v7 = round-14 structure with BK=64.
//  - BM=64, BN=192, BK=64 -> 512 blocks, 16 iters, 24 MFMA/wave/iter
//  - both operands LDS-staged, G4 swizzle (2-way max), 64 KB LDS (2 blk/CU)
//  - prefetch distance 2 (E/O named reg sets), ONE raw barrier per iter
// ---------------------------------------------------------------------------
__global__ __launch_bounds__(256, 2) void qkv_gemm(const float* __restrict__ X,
                                                   const ushort* __restrict__ wt,
                                                   ushort* __restrict__ qws,
                                                   ushort* __restrict__ kws,
                                                   ushort* __restrict__ vtws) {
  __shared__ ushort As[2][64 * 64];    // [64 rows][64 bf16] swizzled, 8 KB each
  __shared__ ushort Bs[2][192 * 64];   // [192 rows][64 bf16] swizzled, 24 KB each
  const int tid = threadIdx.x;
  const int wid = tid >> 6, lane = tid & 63;
  const int lg = lane >> 4, lr = lane & 15;
  const int m0 = (blockIdx.x >> 1) * 64;
  const int n0 = (blockIdx.x & 1) * 192;
  const float QSCL = 0.03125f * 1.44269504f;

  // A staging: idx = tid + 256*i (i=0,1): row=idx>>3, slot=idx&7 (8 floats)
  const int arow = tid >> 3, aslot = tid & 7;
  const float* gA0 = &X[(size_t)(m0 + arow) * C_DIM + aslot * 8];
  const float* gA1 = gA0 + (size_t)32 * C_DIM;
  const int awb0 = sw128(arow, aslot);          // As byte; +4096 for row+32
  // B staging: idx = tid + 256*i (i=0..5): global ushort = tile + idx*8
  const ushort* gBt = wt + (size_t)n0 * 64 + (size_t)tid * 8;
  const int bwb0 = sw128(tid >> 3, tid & 7);    // Bs byte; +4096 per i

  // fragment read bases: A (r,kk): afb[kk] + r*2048 ; B (c,kk): bfb[kk] + c*2048
  const int afb0 = sw128(lr, lg), afb1 = sw128(lr, 4 + lg);
  const int bfb0 = sw128(wid * 48 + lr, lg), bfb1 = sw128(wid * 48 + lr, 4 + lg);

  f32x4 acc[4][3];
#pragma unroll
  for (int r = 0; r < 4; ++r)
#pragma unroll
    for (int c = 0; c < 3; ++c)
      acc[r][c] = f32x4{0.f, 0.f, 0.f, 0.f};

  float4 aE[4], aO[4];
  us8 bE[6], bO[6];

#define LOAD_SET(aS, bS, kt_)                                              \
  {                                                                        \
    aS[0] = *(const float4*)(gA0 + (kt_) * 64);                            \
    aS[1] = *(const float4*)(gA0 + (kt_) * 64 + 4);                        \
    aS[2] = *(const float4*)(gA1 + (kt_) * 64);                            \
    aS[3] = *(const float4*)(gA1 + (kt_) * 64 + 4);                        \
    const ushort* gB_ = gBt + (size_t)(kt_) * 24576;                       \
    bS[0] = *(const us8*)(gB_);                                            \
    bS[1] = *(const us8*)(gB_ + 2048);                                     \
    bS[2] = *(const us8*)(gB_ + 4096);                                     \
    bS[3] = *(const us8*)(gB_ + 6144);                                     \
    bS[4] = *(const us8*)(gB_ + 8192);                                     \
    bS[5] = *(const us8*)(gB_ + 10240);                                    \
  }

#define WRITE_SET(aS, bS, buf)                                             \
  {                                                                        \
    us8 av0, av1;                                                          \
    av0[0] = f2bf(aS[0].x); av0[1] = f2bf(aS[0].y);                        \
    av0[2] = f2bf(aS[0].z); av0[3] = f2bf(aS[0].w);                        \
    av0[4] = f2bf(aS[1].x); av0[5] = f2bf(aS[1].y);                        \
    av0[6] = f2bf(aS[1].z); av0[7] = f2bf(aS[1].w);                        \
    av1[0] = f2bf(aS[2].x); av1[1] = f2bf(aS[2].y);                        \
    av1[2] = f2bf(aS[2].z); av1[3] = f2bf(aS[2].w);                        \
    av1[4] = f2bf(aS[3].x); av1[5] = f2bf(aS[3].y);                        \
    av1[6] = f2bf(aS[3].z); av1[7] = f2bf(aS[3].w);                        \
    *(us8*)((char*)&As[buf][0] + awb0) = av0;                              \
    *(us8*)((char*)&As[buf][0] + awb0 + 4096) = av1;                       \
    _Pragma("unroll")                                                      \
    for (int i = 0; i < 6; ++i)                                            \
      *(us8*)((char*)&Bs[buf][0] + bwb0 + i * 4096) = bS[i];               \
  }

#define COMPUTE(buf)                                                       \
  {                                                                        \
    _Pragma("unroll")                                                      \
    for (int kk = 0; kk < 2; ++kk) {                                       \
      const int afb = kk ? afb1 : afb0;                                    \
      const int bfb = kk ? bfb1 : bfb0;                                    \
      bf16x8 a0 = *(const bf16x8*)((const char*)&As[buf][0] + afb);        \
      bf16x8 a1 = *(const bf16x8*)((const char*)&As[buf][0] + afb + 2048); \
      bf16x8 a2 = *(const bf16x8*)((const char*)&As[buf][0] + afb + 4096); \
      bf16x8 a3 = *(const bf16x8*)((const char*)&As[buf][0] + afb + 6144); \
      _Pragma("unroll")                                                    \
      for (int c = 0; c < 3; ++c) {                                        \
        bf16x8 bf = *(const bf16x8*)((const char*)&Bs[buf][0] + bfb + c * 2048); \
        acc[0][c] = MFMA(a0, bf, acc[0][c]);                               \
        acc[1][c] = MFMA(a1, bf, acc[1][c]);                               \
        acc[2][c] = MFMA(a2, bf, acc[2][c]);                               \
        acc[3][c] = MFMA(a3, bf, acc[3][c]);                               \
      }                                                                    \
    }                                                                      \
  }

  // ---- prologue: tile0 -> LDS buf0 directly; tile1 -> E; tile2 -> O ----
  {
    float4 aT[4];
    us8 bT[6];
    LOAD_SET(aT, bT, 0);
    WRITE_SET(aT, bT, 0);
  }
  LOAD_SET(aE, bE, 1);
  LOAD_SET(aO, bO, 2);
  waitbar();   // tile0 staged & visible

  for (int k2 = 0; k2 < 16; k2 += 2) {
    // ==== even iter kt=k2: write tile k2+1 (E) -> buf1; compute buf0 ====
    WRITE_SET(aE, bE, 1);
    if (k2 + 3 < 16) LOAD_SET(aE, bE, k2 + 3);
    COMPUTE(0);
    waitbar();

    // ==== odd iter kt=k2+1: write tile k2+2 (O) -> buf0; compute buf1 ====
    if (k2 + 2 < 16) WRITE_SET(aO, bO, 0);
    if (k2 + 4 < 16) LOAD_SET(aO, bO, k2 + 4);
    COMPUTE(1);
    waitbar();
  }
#undef LOAD_SET
#undef WRITE_SET
#undef COMPUTE

  // epilogue: C frag layout col=lane&15, row=(lane>>4)*4+j
#pragma unroll
  for (int c = 0; c < 3; ++c) {
    int gc = n0 + wid * 48 + c * 16 + lr;
    int mat = gc >> 7, h = gc & 127;
#pragma unroll
    for (int r = 0; r < 4; ++r) {
#pragma unroll
      for (int j = 0; j < 4; ++j) {
        int gr = m0 + r * 16 + lg * 4 + j;
        float val = acc[r][c][j];
        ushort ov = f2bf(mat == 0 ? val * QSCL : val);
        if (mat == 0) {
          qws[(size_t)gr * H_DIM + h] = ov;
        } else if (mat == 1) {
          kws[(size_t)gr * H_DIM + h] = ov;
        } else {
          int b = gr >> 11, t = gr & 2047;
          vtws[((size_t)b * H_DIM + h) * T_LEN + t] = ov;
        }
      }
    }
  }
}

// ---------------------------------------------------------------------------
// Kernel 2a: flash partial pass, block-cooperative LDS-staged K/V
// (unchanged from round 9).
// ---------------------------------------------------------------------------
__global__ __launch_bounds__(256, 3) void attn_part(const ushort* __restrict__ qws,
                                                    const ushort* __restrict__ kws,
                                                    const ushort* __restrict__ vtws,
                                                    float* __restrict__ pml,
                                                    ushort* __restrict__ pacc,
                                                    float* __restrict__ out) {
  __shared__ ushort Klds[64 * KSTR];
  __shared__ ushort Vlds[128 * VSTR];
  __shared__ ushort Pw[4][16 * PSTR];

  const int tid = threadIdx.x;
  const int wid = tid >> 6, lane = tid & 63;
  const int lg = lane >> 4, lr = lane & 15;
  const int bid = blockIdx.x;
  const int b = bid & 7;
  const int item = bid >> 3;

  int qb, ck;
  bool direct;
  if (item < 8) {
    qb = item; ck = 0; direct = true;
  } else {
    const int p = item - 8;
    direct = false;
    if (p < 12)      { int q = p / 3;        qb = 8 + q;  ck = p - q * 3; }
    else if (p < 28) { int q = (p - 12) >> 2; qb = 12 + q; ck = (p - 12) & 3; }
    else if (p < 48) { int q = (p - 28) / 5; qb = 16 + q; ck = (p - 28) - q * 5; }
    else if (p < 72) { int q = (p - 48) / 6; qb = 20 + q; ck = (p - 48) - q * 6; }
    else if (p < 100){ int q = (p - 72) / 7; qb = 24 + q; ck = (p - 72) - q * 7; }
    else             { int q = (p - 100) >> 3; qb = 28 + q; ck = (p - 100) & 7; }
  }
  const int qi = qb * 4 + wid;
  const int q0 = qi * 16;
  const int nt = qb + 1;
  const int kvt_lo = direct ? 0 : ck * 4;
  const int kvt_hi = direct ? nt : min(ck * 4 + 4, nt);
  const size_t tokbase = (size_t)b * T_LEN;
  const ushort* vb = vtws + (size_t)b * H_DIM * T_LEN;

  const int kr = tid >> 2, kseg = tid & 3;
  const int vr = tid >> 1, vseg = tid & 1;
  const ushort* gK = &kws[(tokbase + kr) * H_DIM + kseg * 32];
  const ushort* gV = &vb[(size_t)vr * T_LEN + vseg * 32];

  bf16x8 qf[4];
#pragma unroll
  for (int hk = 0; hk < 4; ++hk)
    qf[hk] = *(const bf16x8*)&qws[(tokbase + q0 + lr) * H_DIM + hk * 32 + lg * 8];

  f32x4 acc[8];
#pragma unroll
  for (int hf = 0; hf < 8; ++hf) acc[hf] = f32x4{0.f, 0.f, 0.f, 0.f};
  float mrun = -INFINITY, lrun = 0.f;

  ushort* Pme = &Pw[wid][0];

  us8 kreg[4], vreg[4];
#pragma unroll
  for (int i = 0; i < 4; ++i) {
    kreg[i] = *(const us8*)(gK + (size_t)kvt_lo * 64 * H_DIM + i * 8);
    vreg[i] = *(const us8*)(gV + kvt_lo * 64 + i * 8);
  }

  for (int kvt = kvt_lo; kvt < kvt_hi; ++kvt) {
    const int kv0 = kvt * 64;

    __syncthreads();
#pragma unroll
    for (int i = 0; i < 4; ++i) {
      *(us8*)&Klds[kr * KSTR + kseg * 32 + i * 8] = kreg[i];
      *(us8*)&Vlds[vr * VSTR + vseg * 32 + i * 8] = vreg[i];
    }
    if (kvt + 1 < kvt_hi) {
#pragma unroll
      for (int i = 0; i < 4; ++i) {
        kreg[i] = *(const us8*)(gK + (size_t)(kv0 + 64) * H_DIM + i * 8);
        vreg[i] = *(const us8*)(gV + kv0 + 64 + i * 8);
      }
    }
    __syncthreads();

    f32x4 s[4];
#pragma unroll
    for (int c = 0; c < 4; ++c) {
      f32x4 sc = f32x4{0.f, 0.f, 0.f, 0.f};
#pragma unroll
      for (int hk = 0; hk < 4; ++hk) {
        bf16x8 kf = *(const bf16x8*)&Klds[(c * 16 + lr) * KSTR + hk * 32 + lg * 8];
        sc = MFMA(kf, qf[hk], sc);
      }
      s[c] = sc;
    }

    if (kvt == nt - 1) {
#pragma unroll
      for (int c = 0; c < 4; ++c)
#pragma unroll
        for (int j = 0; j < 4; ++j) {
          int kv = kv0 + c * 16 + lg * 4 + j;
          if (kv > q0 + lr) s[c][j] = -INFINITY;
        }
    }

    float mx = s[0][0];
#pragma unroll
    for (int c = 0; c < 4; ++c)
#pragma unroll
      for (int j = 0; j < 4; ++j) mx = fmaxf(mx, s[c][j]);
    mx = fmaxf(mx, __shfl_xor(mx, 16));
    mx = fmaxf(mx, __shfl_xor(mx, 32));

    float mnew = fmaxf(mrun, mx);
    float scold = exp2f(mrun - mnew);

    float rsum = 0.f;
#pragma unroll
    for (int c = 0; c < 4; ++c)
#pragma unroll
      for (int j = 0; j < 4; ++j) {
        float p = exp2f(s[c][j] - mnew);
        s[c][j] = p;
        rsum += p;
      }

#pragma unroll
    for (int c = 0; c < 4; ++c) {
      ushort4 u;
      u.x = f2bf(s[c][0]); u.y = f2bf(s[c][1]);
      u.z = f2bf(s[c][2]); u.w = f2bf(s[c][3]);
      *(ushort4*)&Pme[lr * PSTR + c * 16 + lg * 4] = u;
    }

    bf16x8 v0[8];
#pragma unroll
    for (int hf = 0; hf < 8; ++hf)
      v0[hf] = *(const bf16x8*)&Vlds[(hf * 16 + lr) * VSTR + lg * 8];

    rsum += __shfl_xor(rsum, 16);
    rsum += __shfl_xor(rsum, 32);

    lrun = lrun * scold + rsum;
    mrun = mnew;
#pragma unroll
    for (int hf = 0; hf < 8; ++hf)
#pragma unroll
      for (int j = 0; j < 4; ++j) acc[hf][j] *= scold;

    bf16x8 pa0 = *(const bf16x8*)&Pme[lr * PSTR + lg * 8];
    bf16x8 pa1 = *(const bf16x8*)&Pme[lr * PSTR + 32 + lg * 8];

#pragma unroll
    for (int hf = 0; hf < 8; ++hf)
      acc[hf] = MFMA(v0[hf], pa0, acc[hf]);
#pragma unroll
    for (int hf = 0; hf < 8; ++hf) {
      bf16x8 v1 = *(const bf16x8*)&Vlds[(hf * 16 + lr) * VSTR + 32 + lg * 8];
      acc[hf] = MFMA(v1, pa1, acc[hf]);
    }
  }

  if (direct) {
    float inv = 1.0f / lrun;
    float* op = &out[(tokbase + q0 + lr) * H_DIM + lg * 4];
#pragma unroll
    for (int hf = 0; hf < 8; ++hf) {
      float4 r0 = make_float4(acc[hf][0] * inv, acc[hf][1] * inv,
                              acc[hf][2] * inv, acc[hf][3] * inv);
      *(float4*)(op + hf * 16) = r0;
    }
  } else {
    int base;
    if (qi < 48)       base = (qi - 32) * 3;
    else if (qi < 64)  base = 48 + (qi - 48) * 4;
    else if (qi < 80)  base = 112 + (qi - 64) * 5;
    else if (qi < 96)  base = 192 + (qi - 80) * 6;
    else if (qi < 112) base = 288 + (qi - 96) * 7;
    else               base = 400 + (qi - 112) * 8;
    const size_t slot = (size_t)b * SLOTS_PER_B + base + ck;
    if (lg == 0) {
      pml[slot * 32 + lr] = mrun;
      pml[slot * 32 + 16 + lr] = lrun;
    }
    ushort* ap = &pacc[slot * 2048 + (size_t)lr * 128 + lg * 4];
#pragma unroll
    for (int hf = 0; hf < 8; ++hf) {
      ushort4 u;
      u.x = f2bf(acc[hf][0]); u.y = f2bf(acc[hf][1]);
      u.z = f2bf(acc[hf][2]); u.w = f2bf(acc[hf][3]);
      *(ushort4*)(ap + hf * 16) = u;
    }
  }
}

// ---------------------------------------------------------------------------
// Kernel 2b: online merge of 3..8 partials per (b, qi) for qi >= 32.
// (unchanged)
// ---------------------------------------------------------------------------
__global__ __launch_bounds__(256) void attn_merge(const float* __restrict__ pml,
                                                  const ushort* __restrict__ pacc,
                                                  float* __restrict__ out) {
  const int bid = blockIdx.x;
  const int b = bid & 7, qi = (bid >> 3) + 32;
  int base, nch;
  if (qi < 48)       { base = (qi - 32) * 3;        nch = 3; }
  else if (qi < 64)  { base = 48 + (qi - 48) * 4;   nch = 4; }
  else if (qi < 80)  { base = 112 + (qi - 64) * 5;  nch = 5; }
  else if (qi < 96)  { base = 192 + (qi - 80) * 6;  nch = 6; }
  else if (qi < 112) { base = 288 + (qi - 96) * 7;  nch = 7; }
  else               { base = 400 + (qi - 112) * 8; nch = 8; }
  const size_t slot0 = (size_t)b * SLOTS_PER_B + base;
  const int tid = threadIdx.x;
  const int r = tid >> 4, c0 = (tid & 15) * 8;

  float mrun = -INFINITY, L = 0.f;
  float o[8];
#pragma unroll
  for (int i = 0; i < 8; ++i) o[i] = 0.f;

  for (int ck = 0; ck < nch; ++ck) {
    const size_t s = slot0 + ck;
    float m = pml[s * 32 + r];
    float l = pml[s * 32 + 16 + r];
    float mn = fmaxf(mrun, m);
    float sc = exp2f(mrun - mn);
    float w  = exp2f(m - mn);
    L = L * sc + w * l;
    const ushort* ap = &pacc[s * 2048 + (size_t)r * 128 + c0];
    ushort4 u0 = *(const ushort4*)ap;
    ushort4 u1 = *(const ushort4*)(ap + 4);
    o[0] = o[0] * sc + w * bf2f(u0.x); o[1] = o[1] * sc + w * bf2f(u0.y);
    o[2] = o[2] * sc + w * bf2f(u0.z); o[3] = o[3] * sc + w * bf2f(u0.w);
    o[4] = o[4] * sc + w * bf2f(u1.x); o[5] = o[5] * sc + w * bf2f(u1.y);
    o[6] = o[6] * sc + w * bf2f(u1.z); o[7] = o[7] * sc + w * bf2f(u1.w);
    mrun = mn;
  }
  float invL = 1.0f / L;
  float4 r0 = make_float4(o[0] * invL, o[1] * invL, o[2] * invL, o[3] * invL);
  float4 r1 = make_float4(o[4] * invL, o[5] * invL, o[6] * invL, o[7] * invL);
  float* op = &out[((size_t)b * T_LEN + qi * 16 + r) * H_DIM + c0];
  *(float4*)op = r0;
  *(float4*)(op + 4) = r1;
}

// ---------------------------------------------------------------------------
// ws layout identical to rounds 8-16 (total 30,670,848 B, proven fit):
//   [0, 786432) wt_t (dead after qkv_gemm; pml overlaps, 540,672 B)
//   qws / kws / vtws ; pacc = 8*528 slots * 2048 bf16
// ---------------------------------------------------------------------------
extern "C" void kernel_launch(void* const* d_in, const int* in_sizes, int n_in,
                              void* d_out, int out_size, void* d_ws, size_t ws_size,
                              hipStream_t stream) {
  const float* emb = (const float*)d_in[0];
  const float* Wq  = (const float*)d_in[1];
  const float* Wk  = (const float*)d_in[2];
  const float* Wv  = (const float*)d_in[3];
  float* out = (float*)d_out;

  ushort* wt   = (ushort*)d_ws;
  ushort* qws  = wt  + (size_t)N_COLS * C_DIM;
  ushort* kws  = qws + (size_t)M_ROWS * H_DIM;
  ushort* vtws = kws + (size_t)M_ROWS * H_DIM;
  ushort* pacc = vtws + (size_t)8 * H_DIM * T_LEN;
  float*  pml  = (float*)d_ws;   // overlaps dead wt region

  wt_convert<<<(N_COLS * C_DIM) / 256, 256, 0, stream>>>(Wq, Wk, Wv, wt);
  qkv_gemm<<<(M_ROWS / 64) * 2, 256, 0, stream>>>(emb, wt, qws, kws, vtws);
  attn_part<<<8 * 140, 256, 0, stream>>>(qws, kws, vtws, pml, pacc, out);
  attn_merge<<<8 * 96, 256, 0, stream>>>(pml, pacc, out);
}

// Round 18
// 78.623 us; speedup vs baseline: 1.1415x; 1.0108x over previous
//
#include <hip/hip_runtime.h>
#include <hip/hip_bf16.h>

typedef __bf16 bf16x8 __attribute__((ext_vector_type(8)));
typedef float f32x4 __attribute__((ext_vector_type(4)));
typedef ushort us8 __attribute__((ext_vector_type(8)));

#define MFMA(a, b, c) __builtin_amdgcn_mfma_f32_16x16x32_bf16((a), (b), (c), 0, 0, 0)

static constexpr int T_LEN = 2048;
static constexpr int C_DIM = 1024;
static constexpr int H_DIM = 128;
static constexpr int M_ROWS = 8 * 2048;    // 16384
static constexpr int N_COLS = 384;         // 3 * 128
static constexpr int SLOTS_PER_B = 528;    // partial slots (qi>=32)
static constexpr int PSTR = 72;            // P buffer row stride
static constexpr int KSTR = 136;           // K LDS row stride (272B, 2-way max)
static constexpr int VSTR = 72;            // V LDS row stride (144B, 2-way max)

__device__ __forceinline__ ushort f2bf(float f) {
  union { float f; unsigned u; } v; v.f = f;
  unsigned u = v.u;
  u += 0x7fffu + ((u >> 16) & 1u);
  return (ushort)(u >> 16);
}
__device__ __forceinline__ float bf2f(ushort u) {
  union { unsigned u; float f; } v; v.u = (unsigned)u << 16;
  return v.f;
}

// raw barrier: lgkmcnt(0) for LDS visibility, NO vmcnt drain.
__device__ __forceinline__ void waitbar() {
  asm volatile("s_waitcnt lgkmcnt(0)" ::: "memory");
  __builtin_amdgcn_s_barrier();
  __builtin_amdgcn_sched_barrier(0);
}

// paired-row swizzled LDS byte address for logical (row, 16B-slot):
//   [R][32 ushorts] stored as [R/2][64 ushorts];
//   byte = (row>>1)*128 + (row&1)*64 + ((slot*16) ^ (((row>>1)&3)<<4))
// (round-14-proven: bijective, frag reads & staged writes <=2-way = free)
__device__ __forceinline__ int swz_byte(int row, int slot) {
  return (row >> 1) * 128 + (row & 1) * 64 + ((slot * 16) ^ (((row >> 1) & 3) << 4));
}

// ---------------------------------------------------------------------------
// Kernel 0: Wq/Wk/Wv fp32 [1024][128] -> bf16 wt_t, BK=32 K-STEP-TILED:
//   wt_t[(kt*384 + gc)*32 + kk] = W(c = kt*32+kk, gc)   kt=0..31
// Each K-step's 192-col B-half is a contiguous 12 KB block.
// ---------------------------------------------------------------------------
__global__ void wt_convert(const float* __restrict__ Wq,
                           const float* __restrict__ Wk,
                           const float* __restrict__ Wv,
                           ushort* __restrict__ wt) {
  int o = blockIdx.x * 256 + threadIdx.x;   // 0..393215
  int kt = o / 12288;                        // 384*32
  int rem = o - kt * 12288;
  int gc = rem >> 5;
  int kk = rem & 31;
  int c  = kt * 32 + kk;
  int mat = gc >> 7;
  int h   = gc & 127;
  const float* W = (mat == 0) ? Wq : ((mat == 1) ? Wk : Wv);
  wt[o] = f2bf(W[c * H_DIM + h]);
}

// ---------------------------------------------------------------------------
// Kernel 1: fused QKV projection v8 — round-14 machinery at round-12 shape.
//  - BM=32, BN=192, BK=32 -> 1024 blocks (4/CU, 16 waves/CU), LDS 28 KB
//  - both operands LDS-staged, paired-row swizzle (conflict-free, r14-proven)
//  - prefetch distance 2 (E/O named reg sets), ONE raw barrier per iter
//  - 6 MFMA/wave/iter, 32 iters; cross-block wave overlap hides latency
// ---------------------------------------------------------------------------
__global__ __launch_bounds__(256, 4) void qkv_gemm(const float* __restrict__ X,
                                                   const ushort* __restrict__ wt,
                                                   ushort* __restrict__ qws,
                                                   ushort* __restrict__ kws,
                                                   ushort* __restrict__ vtws) {
  __shared__ ushort As[2][16 * 64];    // logical [32][32] paired, 2 KB each
  __shared__ ushort Bs[2][96 * 64];    // logical [192][32] paired, 12 KB each
  const int tid = threadIdx.x;
  const int wid = tid >> 6, lane = tid & 63;
  const int lg = lane >> 4, lr = lane & 15;
  const int m0 = (blockIdx.x >> 1) * 32;
  const int n0 = (blockIdx.x & 1) * 192;
  const float QSCL = 0.03125f * 1.44269504f;

  // A staging: thread -> row tid>>3 (0..31), 4 floats at col (tid&7)*4
  const int arow = tid >> 3, acol = tid & 7;
  const float* gA = &X[(size_t)(m0 + arow) * C_DIM + acol * 4];
  const int awb = swz_byte(arow, acol >> 1) + (acol & 1) * 8;

  // B staging: slot s = tid + 256k (k=0..2); global = wt + kt*12288 + n0*32 + s*8
  const ushort* gBt = wt + (size_t)n0 * 32 + (size_t)tid * 8;
  const int bwb0 = swz_byte(tid >> 2, tid & 3);   // +4096 per k

  // fragment read bases (row-step 16 -> +1024 B exactly; &3 invariant)
  const int afb = swz_byte(lr, lg);               // a1 at +1024
  const int bfb = swz_byte(wid * 48 + lr, lg);    // +c*1024, c=0..2

  f32x4 acc[2][3];
#pragma unroll
  for (int r = 0; r < 2; ++r)
#pragma unroll
    for (int c = 0; c < 3; ++c)
      acc[r][c] = f32x4{0.f, 0.f, 0.f, 0.f};

  float4 aE, aO;
  us8 bE0, bE1, bE2, bO0, bO1, bO2;

#define LOAD_A(dst, kt_) dst = *(const float4*)(gA + (kt_) * 32);
#define LOAD_B(b0, b1, b2, kt_)                                   \
  {                                                               \
    const ushort* g_ = gBt + (size_t)(kt_) * 12288;               \
    b0 = *(const us8*)(g_);                                       \
    b1 = *(const us8*)(g_ + 2048);                                \
    b2 = *(const us8*)(g_ + 4096);                                \
  }
#define WRITE_SET(aS, b0, b1, b2, buf)                            \
  {                                                               \
    ushort4 av;                                                   \
    av.x = f2bf(aS.x); av.y = f2bf(aS.y);                         \
    av.z = f2bf(aS.z); av.w = f2bf(aS.w);                         \
    *(ushort4*)((char*)&As[buf][0] + awb) = av;                   \
    *(us8*)((char*)&Bs[buf][0] + bwb0) = b0;                      \
    *(us8*)((char*)&Bs[buf][0] + bwb0 + 4096) = b1;               \
    *(us8*)((char*)&Bs[buf][0] + bwb0 + 8192) = b2;               \
  }
#define COMPUTE(buf)                                              \
  {                                                               \
    bf16x8 a0 = *(const bf16x8*)((const char*)&As[buf][0] + afb); \
    bf16x8 a1 = *(const bf16x8*)((const char*)&As[buf][0] + afb + 1024); \
    _Pragma("unroll")                                             \
    for (int c = 0; c < 3; ++c) {                                 \
      bf16x8 bf = *(const bf16x8*)((const char*)&Bs[buf][0] + bfb + c * 1024); \
      acc[0][c] = MFMA(a0, bf, acc[0][c]);                        \
      acc[1][c] = MFMA(a1, bf, acc[1][c]);                        \
    }                                                             \
  }

  // ---- prologue: tile0 -> buf0 directly; tile1 -> E; tile2 -> O ----
  {
    float4 aT;
    us8 bT0, bT1, bT2;
    LOAD_A(aT, 0);
    LOAD_B(bT0, bT1, bT2, 0);
    WRITE_SET(aT, bT0, bT1, bT2, 0);
  }
  LOAD_A(aE, 1); LOAD_B(bE0, bE1, bE2, 1);
  LOAD_A(aO, 2); LOAD_B(bO0, bO1, bO2, 2);
  waitbar();   // tile0 staged & visible

  for (int k2 = 0; k2 < 32; k2 += 2) {
    // ==== even iter kt=k2: write tile k2+1 (E) -> buf1; compute buf0 ====
    WRITE_SET(aE, bE0, bE1, bE2, 1);
    if (k2 + 3 < 32) { LOAD_A(aE, k2 + 3); LOAD_B(bE0, bE1, bE2, k2 + 3); }
    COMPUTE(0);
    waitbar();

    // ==== odd iter kt=k2+1: write tile k2+2 (O) -> buf0; compute buf1 ====
    if (k2 + 2 < 32) WRITE_SET(aO, bO0, bO1, bO2, 0);
    if (k2 + 4 < 32) { LOAD_A(aO, k2 + 4); LOAD_B(bO0, bO1, bO2, k2 + 4); }
    COMPUTE(1);
    waitbar();
  }
#undef LOAD_A
#undef LOAD_B
#undef WRITE_SET
#undef COMPUTE

  // epilogue: C frag layout col=lane&15, row=(lane>>4)*4+j
#pragma unroll
  for (int c = 0; c < 3; ++c) {
    int gc = n0 + wid * 48 + c * 16 + lr;
    int mat = gc >> 7, h = gc & 127;
#pragma unroll
    for (int r = 0; r < 2; ++r) {
#pragma unroll
      for (int j = 0; j < 4; ++j) {
        int gr = m0 + r * 16 + lg * 4 + j;
        float val = acc[r][c][j];
        ushort ov = f2bf(mat == 0 ? val * QSCL : val);
        if (mat == 0) {
          qws[(size_t)gr * H_DIM + h] = ov;
        } else if (mat == 1) {
          kws[(size_t)gr * H_DIM + h] = ov;
        } else {
          int b = gr >> 11, t = gr & 2047;
          vtws[((size_t)b * H_DIM + h) * T_LEN + t] = ov;
        }
      }
    }
  }
}

// ---------------------------------------------------------------------------
// Kernel 2a: flash partial pass, block-cooperative LDS-staged K/V
// (unchanged from round 9).
// ---------------------------------------------------------------------------
__global__ __launch_bounds__(256, 3) void attn_part(const ushort* __restrict__ qws,
                                                    const ushort* __restrict__ kws,
                                                    const ushort* __restrict__ vtws,
                                                    float* __restrict__ pml,
                                                    ushort* __restrict__ pacc,
                                                    float* __restrict__ out) {
  __shared__ ushort Klds[64 * KSTR];
  __shared__ ushort Vlds[128 * VSTR];
  __shared__ ushort Pw[4][16 * PSTR];

  const int tid = threadIdx.x;
  const int wid = tid >> 6, lane = tid & 63;
  const int lg = lane >> 4, lr = lane & 15;
  const int bid = blockIdx.x;
  const int b = bid & 7;
  const int item = bid >> 3;

  int qb, ck;
  bool direct;
  if (item < 8) {
    qb = item; ck = 0; direct = true;
  } else {
    const int p = item - 8;
    direct = false;
    if (p < 12)      { int q = p / 3;        qb = 8 + q;  ck = p - q * 3; }
    else if (p < 28) { int q = (p - 12) >> 2; qb = 12 + q; ck = (p - 12) & 3; }
    else if (p < 48) { int q = (p - 28) / 5; qb = 16 + q; ck = (p - 28) - q * 5; }
    else if (p < 72) { int q = (p - 48) / 6; qb = 20 + q; ck = (p - 48) - q * 6; }
    else if (p < 100){ int q = (p - 72) / 7; qb = 24 + q; ck = (p - 72) - q * 7; }
    else             { int q = (p - 100) >> 3; qb = 28 + q; ck = (p - 100) & 7; }
  }
  const int qi = qb * 4 + wid;
  const int q0 = qi * 16;
  const int nt = qb + 1;
  const int kvt_lo = direct ? 0 : ck * 4;
  const int kvt_hi = direct ? nt : min(ck * 4 + 4, nt);
  const size_t tokbase = (size_t)b * T_LEN;
  const ushort* vb = vtws + (size_t)b * H_DIM * T_LEN;

  const int kr = tid >> 2, kseg = tid & 3;
  const int vr = tid >> 1, vseg = tid & 1;
  const ushort* gK = &kws[(tokbase + kr) * H_DIM + kseg * 32];
  const ushort* gV = &vb[(size_t)vr * T_LEN + vseg * 32];

  bf16x8 qf[4];
#pragma unroll
  for (int hk = 0; hk < 4; ++hk)
    qf[hk] = *(const bf16x8*)&qws[(tokbase + q0 + lr) * H_DIM + hk * 32 + lg * 8];

  f32x4 acc[8];
#pragma unroll
  for (int hf = 0; hf < 8; ++hf) acc[hf] = f32x4{0.f, 0.f, 0.f, 0.f};
  float mrun = -INFINITY, lrun = 0.f;

  ushort* Pme = &Pw[wid][0];

  us8 kreg[4], vreg[4];
#pragma unroll
  for (int i = 0; i < 4; ++i) {
    kreg[i] = *(const us8*)(gK + (size_t)kvt_lo * 64 * H_DIM + i * 8);
    vreg[i] = *(const us8*)(gV + kvt_lo * 64 + i * 8);
  }

  for (int kvt = kvt_lo; kvt < kvt_hi; ++kvt) {
    const int kv0 = kvt * 64;

    __syncthreads();
#pragma unroll
    for (int i = 0; i < 4; ++i) {
      *(us8*)&Klds[kr * KSTR + kseg * 32 + i * 8] = kreg[i];
      *(us8*)&Vlds[vr * VSTR + vseg * 32 + i * 8] = vreg[i];
    }
    if (kvt + 1 < kvt_hi) {
#pragma unroll
      for (int i = 0; i < 4; ++i) {
        kreg[i] = *(const us8*)(gK + (size_t)(kv0 + 64) * H_DIM + i * 8);
        vreg[i] = *(const us8*)(gV + kv0 + 64 + i * 8);
      }
    }
    __syncthreads();

    f32x4 s[4];
#pragma unroll
    for (int c = 0; c < 4; ++c) {
      f32x4 sc = f32x4{0.f, 0.f, 0.f, 0.f};
#pragma unroll
      for (int hk = 0; hk < 4; ++hk) {
        bf16x8 kf = *(const bf16x8*)&Klds[(c * 16 + lr) * KSTR + hk * 32 + lg * 8];
        sc = MFMA(kf, qf[hk], sc);
      }
      s[c] = sc;
    }

    if (kvt == nt - 1) {
#pragma unroll
      for (int c = 0; c < 4; ++c)
#pragma unroll
        for (int j = 0; j < 4; ++j) {
          int kv = kv0 + c * 16 + lg * 4 + j;
          if (kv > q0 + lr) s[c][j] = -INFINITY;
        }
    }

    float mx = s[0][0];
#pragma unroll
    for (int c = 0; c < 4; ++c)
#pragma unroll
      for (int j = 0; j < 4; ++j) mx = fmaxf(mx, s[c][j]);
    mx = fmaxf(mx, __shfl_xor(mx, 16));
    mx = fmaxf(mx, __shfl_xor(mx, 32));

    float mnew = fmaxf(mrun, mx);
    float scold = exp2f(mrun - mnew);

    float rsum = 0.f;
#pragma unroll
    for (int c = 0; c < 4; ++c)
#pragma unroll
      for (int j = 0; j < 4; ++j) {
        float p = exp2f(s[c][j] - mnew);
        s[c][j] = p;
        rsum += p;
      }

#pragma unroll
    for (int c = 0; c < 4; ++c) {
      ushort4 u;
      u.x = f2bf(s[c][0]); u.y = f2bf(s[c][1]);
      u.z = f2bf(s[c][2]); u.w = f2bf(s[c][3]);
      *(ushort4*)&Pme[lr * PSTR + c * 16 + lg * 4] = u;
    }

    bf16x8 v0[8];
#pragma unroll
    for (int hf = 0; hf < 8; ++hf)
      v0[hf] = *(const bf16x8*)&Vlds[(hf * 16 + lr) * VSTR + lg * 8];

    rsum += __shfl_xor(rsum, 16);
    rsum += __shfl_xor(rsum, 32);

    lrun = lrun * scold + rsum;
    mrun = mnew;
#pragma unroll
    for (int hf = 0; hf < 8; ++hf)
#pragma unroll
      for (int j = 0; j < 4; ++j) acc[hf][j] *= scold;

    bf16x8 pa0 = *(const bf16x8*)&Pme[lr * PSTR + lg * 8];
    bf16x8 pa1 = *(const bf16x8*)&Pme[lr * PSTR + 32 + lg * 8];

#pragma unroll
    for (int hf = 0; hf < 8; ++hf)
      acc[hf] = MFMA(v0[hf], pa0, acc[hf]);
#pragma unroll
    for (int hf = 0; hf < 8; ++hf) {
      bf16x8 v1 = *(const bf16x8*)&Vlds[(hf * 16 + lr) * VSTR + 32 + lg * 8];
      acc[hf] = MFMA(v1, pa1, acc[hf]);
    }
  }

  if (direct) {
    float inv = 1.0f / lrun;
    float* op = &out[(tokbase + q0 + lr) * H_DIM + lg * 4];
#pragma unroll
    for (int hf = 0; hf < 8; ++hf) {
      float4 r0 = make_float4(acc[hf][0] * inv, acc[hf][1] * inv,
                              acc[hf][2] * inv, acc[hf][3] * inv);
      *(float4*)(op + hf * 16) = r0;
    }
  } else {
    int base;
    if (qi < 48)       base = (qi - 32) * 3;
    else if (qi < 64)  base = 48 + (qi - 48) * 4;
    else if (qi < 80)  base = 112 + (qi - 64) * 5;
    else if (qi < 96)  base = 192 + (qi - 80) * 6;
    else if (qi < 112) base = 288 + (qi - 96) * 7;
    else               base = 400 + (qi - 112) * 8;
    const size_t slot = (size_t)b * SLOTS_PER_B + base + ck;
    if (lg == 0) {
      pml[slot * 32 + lr] = mrun;
      pml[slot * 32 + 16 + lr] = lrun;
    }
    ushort* ap = &pacc[slot * 2048 + (size_t)lr * 128 + lg * 4];
#pragma unroll
    for (int hf = 0; hf < 8; ++hf) {
      ushort4 u;
      u.x = f2bf(acc[hf][0]); u.y = f2bf(acc[hf][1]);
      u.z = f2bf(acc[hf][2]); u.w = f2bf(acc[hf][3]);
      *(ushort4*)(ap + hf * 16) = u;
    }
  }
}

// ---------------------------------------------------------------------------
// Kernel 2b: online merge of 3..8 partials per (b, qi) for qi >= 32.
// (unchanged)
// ---------------------------------------------------------------------------
__global__ __launch_bounds__(256) void attn_merge(const float* __restrict__ pml,
                                                  const ushort* __restrict__ pacc,
                                                  float* __restrict__ out) {
  const int bid = blockIdx.x;
  const int b = bid & 7, qi = (bid >> 3) + 32;
  int base, nch;
  if (qi < 48)       { base = (qi - 32) * 3;        nch = 3; }
  else if (qi < 64)  { base = 48 + (qi - 48) * 4;   nch = 4; }
  else if (qi < 80)  { base = 112 + (qi - 64) * 5;  nch = 5; }
  else if (qi < 96)  { base = 192 + (qi - 80) * 6;  nch = 6; }
  else if (qi < 112) { base = 288 + (qi - 96) * 7;  nch = 7; }
  else               { base = 400 + (qi - 112) * 8; nch = 8; }
  const size_t slot0 = (size_t)b * SLOTS_PER_B + base;
  const int tid = threadIdx.x;
  const int r = tid >> 4, c0 = (tid & 15) * 8;

  float mrun = -INFINITY, L = 0.f;
  float o[8];
#pragma unroll
  for (int i = 0; i < 8; ++i) o[i] = 0.f;

  for (int ck = 0; ck < nch; ++ck) {
    const size_t s = slot0 + ck;
    float m = pml[s * 32 + r];
    float l = pml[s * 32 + 16 + r];
    float mn = fmaxf(mrun, m);
    float sc = exp2f(mrun - mn);
    float w  = exp2f(m - mn);
    L = L * sc + w * l;
    const ushort* ap = &pacc[s * 2048 + (size_t)r * 128 + c0];
    ushort4 u0 = *(const ushort4*)ap;
    ushort4 u1 = *(const ushort4*)(ap + 4);
    o[0] = o[0] * sc + w * bf2f(u0.x); o[1] = o[1] * sc + w * bf2f(u0.y);
    o[2] = o[2] * sc + w * bf2f(u0.z); o[3] = o[3] * sc + w * bf2f(u0.w);
    o[4] = o[4] * sc + w * bf2f(u1.x); o[5] = o[5] * sc + w * bf2f(u1.y);
    o[6] = o[6] * sc + w * bf2f(u1.z); o[7] = o[7] * sc + w * bf2f(u1.w);
    mrun = mn;
  }
  float invL = 1.0f / L;
  float4 r0 = make_float4(o[0] * invL, o[1] * invL, o[2] * invL, o[3] * invL);
  float4 r1 = make_float4(o[4] * invL, o[5] * invL, o[6] * invL, o[7] * invL);
  float* op = &out[((size_t)b * T_LEN + qi * 16 + r) * H_DIM + c0];
  *(float4*)op = r0;
  *(float4*)(op + 4) = r1;
}

// ---------------------------------------------------------------------------
// ws layout identical to rounds 8-17 (total 30,670,848 B, proven fit):
//   [0, 786432) wt_t (dead after qkv_gemm; pml overlaps, 540,672 B)
//   qws / kws / vtws ; pacc = 8*528 slots * 2048 bf16
// ---------------------------------------------------------------------------
extern "C" void kernel_launch(void* const* d_in, const int* in_sizes, int n_in,
                              void* d_out, int out_size, void* d_ws, size_t ws_size,
                              hipStream_t stream) {
  const float* emb = (const float*)d_in[0];
  const float* Wq  = (const float*)d_in[1];
  const float* Wk  = (const float*)d_in[2];
  const float* Wv  = (const float*)d_in[3];
  float* out = (float*)d_out;

  ushort* wt   = (ushort*)d_ws;
  ushort* qws  = wt  + (size_t)N_COLS * C_DIM;
  ushort* kws  = qws + (size_t)M_ROWS * H_DIM;
  ushort* vtws = kws + (size_t)M_ROWS * H_DIM;
  ushort* pacc = vtws + (size_t)8 * H_DIM * T_LEN;
  float*  pml  = (float*)d_ws;   // overlaps dead wt region

  wt_convert<<<(N_COLS * C_DIM) / 256, 256, 0, stream>>>(Wq, Wk, Wv, wt);
  qkv_gemm<<<(M_ROWS / 32) * 2, 256, 0, stream>>>(emb, wt, qws, kws, vtws);
  attn_part<<<8 * 140, 256, 0, stream>>>(qws, kws, vtws, pml, pacc, out);
  attn_merge<<<8 * 96, 256, 0, stream>>>(pml, pacc, out);
}

// Round 19
// 77.941 us; speedup vs baseline: 1.1515x; 1.0087x over previous
//
#include <hip/hip_runtime.h>
#include <hip/hip_bf16.h>

typedef __bf16 bf16x8 __attribute__((ext_vector_type(8)));
typedef float f32x4 __attribute__((ext_vector_type(4)));
typedef ushort us8 __attribute__((ext_vector_type(8)));

#define MFMA(a, b, c) __builtin_amdgcn_mfma_f32_16x16x32_bf16((a), (b), (c), 0, 0, 0)

static constexpr int T_LEN = 2048;
static constexpr int C_DIM = 1024;
static constexpr int H_DIM = 128;
static constexpr int M_ROWS = 8 * 2048;    // 16384
static constexpr int N_COLS = 384;         // 3 * 128
static constexpr int SLOTS_PER_B = 528;    // partial slots (qi>=32)
static constexpr int PSTR = 72;            // P buffer row stride
static constexpr int KSTR = 136;           // K LDS row stride (272B, 2-way max)
static constexpr int VSTR = 72;            // V LDS row stride (144B, 2-way max)

__device__ __forceinline__ ushort f2bf(float f) {
  union { float f; unsigned u; } v; v.f = f;
  unsigned u = v.u;
  u += 0x7fffu + ((u >> 16) & 1u);
  return (ushort)(u >> 16);
}
__device__ __forceinline__ float bf2f(ushort u) {
  union { unsigned u; float f; } v; v.u = (unsigned)u << 16;
  return v.f;
}

// async global->LDS: 16B/lane; global src per-lane, LDS dest wave-uniform.
__device__ __forceinline__ void gl2lds16(const ushort* g, ushort* l) {
  __builtin_amdgcn_global_load_lds(
      (const __attribute__((address_space(1))) unsigned int*)(const void*)g,
      (__attribute__((address_space(3))) unsigned int*)(void*)l, 16, 0, 0);
}

// G4-standard swizzle for 128B rows (r17-proven, 0 conflicts measured):
__device__ __forceinline__ int sw128(int row, int slot) {
  return row * 128 + ((slot * 16) ^ ((row & 7) << 4));
}

// vmcnt(N) + lgkmcnt(0) + barrier + sched fence. vmcnt BEFORE the barrier:
// every wave drains its own async B-loads to <=N, so after the barrier ALL
// waves' staged chunks are visible (the m201 cross-wave pattern).
#define SYNCV(VMC)                                                   \
  asm volatile("s_waitcnt vmcnt(" #VMC ")" ::: "memory");            \
  asm volatile("s_waitcnt lgkmcnt(0)" ::: "memory");                 \
  __builtin_amdgcn_s_barrier();                                      \
  __builtin_amdgcn_sched_barrier(0);

// ---------------------------------------------------------------------------
// Kernel 0: Wq/Wk/Wv fp32 [1024][128] -> bf16 wt, FRAGMENT-LINEAR per
// (kt, half): wt[((kt*2+half)*24 + fs)*512 + lane*8 + j] holds
//   B col gc = half*192 + (fs%12)*16 + (lane&15),
//   k      c = kt*64 + (fs/12)*32 + (lane>>4)*8 + j.
// Each (kt,half) B-tile = contiguous 24 KB; gl2lds src/dst both linear.
// ---------------------------------------------------------------------------
__global__ void wt_convert(const float* __restrict__ Wq,
                           const float* __restrict__ Wk,
                           const float* __restrict__ Wv,
                           ushort* __restrict__ wt) {
  int o = blockIdx.x * 256 + threadIdx.x;   // 0..393215
  int kthalf = o / 12288;                    // 0..31
  int rem = o - kthalf * 12288;
  int fs = rem >> 9;                         // 0..23
  int li = rem & 511;
  int lane = li >> 3, j = li & 7;
  int kt = kthalf >> 1, half = kthalf & 1;
  int kk = fs / 12, cg = fs - kk * 12;
  int gc = half * 192 + cg * 16 + (lane & 15);
  int c  = kt * 64 + kk * 32 + (lane >> 4) * 8 + j;
  int mat = gc >> 7, h = gc & 127;
  const float* W = (mat == 0) ? Wq : ((mat == 1) ? Wk : Wv);
  wt[o] = f2bf(W[c * H_DIM + h]);
}

// ---------------------------------------------------------------------------
// Kernel 1: fused QKV projection v10 = r17 structure, B via global_load_lds
// with counted pre-barrier vmcnt (T3/T4). BM=64, BN=192, BK=64, 512 blocks.
//  - B: 6x gl2lds(16B)/thread -> Bs frag-linear (no regs, no ds_writes)
//  - A: r17 reg->LDS path, sw128 swizzle, E/O prefetch distance 2
//  - per iter: issue B(k+1) + write A(k+1) + load A(k+3) + 24 MFMA,
//    then vmcnt(4)+lgkm(0)+barrier (A(k+3) stays in flight across barrier)
// ---------------------------------------------------------------------------
__global__ __launch_bounds__(256, 2) void qkv_gemm(const float* __restrict__ X,
                                                   const ushort* __restrict__ wt,
                                                   ushort* __restrict__ qws,
                                                   ushort* __restrict__ kws,
                                                   ushort* __restrict__ vtws) {
  __shared__ ushort As[2][64 * 64];    // [64][64] sw128, 8 KB each
  __shared__ ushort Bs[2][24 * 512];   // 24 frag-chunks x 1 KB, 24 KB each
  const int tid = threadIdx.x;
  const int wid = tid >> 6, lane = tid & 63;
  const int lg = lane >> 4, lr = lane & 15;
  const int m0 = (blockIdx.x >> 1) * 64;
  const int n0h = blockIdx.x & 1;
  const int n0 = n0h * 192;
  const float QSCL = 0.03125f * 1.44269504f;

  // A staging (r17): row=tid>>3 (0..31) and +32; 8 floats at (tid&7)*8
  const int arow = tid >> 3, aslot = tid & 7;
  const float* gA0 = &X[(size_t)(m0 + arow) * C_DIM + aslot * 8];
  const float* gA1 = gA0 + (size_t)32 * C_DIM;
  const int awb0 = sw128(arow, aslot);          // +4096 for row+32

  // A fragment read bases (r17): + r*2048 for r=0..3
  const int afb0 = sw128(lr, lg), afb1 = sw128(lr, 4 + lg);

  f32x4 acc[4][3];
#pragma unroll
  for (int r = 0; r < 4; ++r)
#pragma unroll
    for (int c = 0; c < 3; ++c)
      acc[r][c] = f32x4{0.f, 0.f, 0.f, 0.f};

  float4 aE[4], aO[4];

#define LOAD_A(aS, kt_)                                                    \
  {                                                                        \
    aS[0] = *(const float4*)(gA0 + (kt_) * 64);                            \
    aS[1] = *(const float4*)(gA0 + (kt_) * 64 + 4);                        \
    aS[2] = *(const float4*)(gA1 + (kt_) * 64);                            \
    aS[3] = *(const float4*)(gA1 + (kt_) * 64 + 4);                        \
  }
#define WRITE_A(aS, buf)                                                   \
  {                                                                        \
    us8 av0, av1;                                                          \
    av0[0] = f2bf(aS[0].x); av0[1] = f2bf(aS[0].y);                        \
    av0[2] = f2bf(aS[0].z); av0[3] = f2bf(aS[0].w);                        \
    av0[4] = f2bf(aS[1].x); av0[5] = f2bf(aS[1].y);                        \
    av0[6] = f2bf(aS[1].z); av0[7] = f2bf(aS[1].w);                        \
    av1[0] = f2bf(aS[2].x); av1[1] = f2bf(aS[2].y);                        \
    av1[2] = f2bf(aS[2].z); av1[3] = f2bf(aS[2].w);                        \
    av1[4] = f2bf(aS[3].x); av1[5] = f2bf(aS[3].y);                        \
    av1[6] = f2bf(aS[3].z); av1[7] = f2bf(aS[3].w);                        \
    *(us8*)((char*)&As[buf][0] + awb0) = av0;                              \
    *(us8*)((char*)&As[buf][0] + awb0 + 4096) = av1;                       \
  }
#define STAGE_B(kt_, buf_)                                                 \
  {                                                                        \
    const ushort* gB_ = wt + (size_t)(((kt_) * 2 + n0h) * 24) * 512        \
                          + (size_t)lane * 8;                              \
    _Pragma("unroll")                                                      \
    for (int jj = 0; jj < 6; ++jj)                                         \
      gl2lds16(gB_ + (size_t)(wid + 4 * jj) * 512,                         \
               &Bs[buf_][(wid + 4 * jj) * 512]);                           \
  }
#define COMPUTE(buf)                                                       \
  {                                                                        \
    _Pragma("unroll")                                                      \
    for (int kk = 0; kk < 2; ++kk) {                                       \
      const int afb = kk ? afb1 : afb0;                                    \
      bf16x8 a0 = *(const bf16x8*)((const char*)&As[buf][0] + afb);        \
      bf16x8 a1 = *(const bf16x8*)((const char*)&As[buf][0] + afb + 2048); \
      bf16x8 a2 = *(const bf16x8*)((const char*)&As[buf][0] + afb + 4096); \
      bf16x8 a3 = *(const bf16x8*)((const char*)&As[buf][0] + afb + 6144); \
      _Pragma("unroll")                                                    \
      for (int c = 0; c < 3; ++c) {                                        \
        bf16x8 bf = *(const bf16x8*)&Bs[buf][(kk * 12 + wid * 3 + c) * 512 \
                                            + lane * 8];                   \
        acc[0][c] = MFMA(a0, bf, acc[0][c]);                               \
        acc[1][c] = MFMA(a1, bf, acc[1][c]);                               \
        acc[2][c] = MFMA(a2, bf, acc[2][c]);                               \
        acc[3][c] = MFMA(a3, bf, acc[3][c]);                               \
      }                                                                    \
    }                                                                      \
  }

  // ---- prologue: B(0) async -> Bs[0]; A(0) -> As[0]; A(1)->E, A(2)->O ----
  STAGE_B(0, 0);
  {
    float4 aT[4];
    LOAD_A(aT, 0);
    WRITE_A(aT, 0);          // reg-dep forces A(0) loads complete
  }
  LOAD_A(aE, 1);
  LOAD_A(aO, 2);
  SYNCV(8);                  // B(0) done (A(1)+A(2)=8 newer allowed in flight)

  // ---- main loop kt = 0..12 (all guards true) ----
  for (int kt = 0; kt < 13; ++kt) {
    const int cur = kt & 1;
    STAGE_B(kt + 1, cur ^ 1);
    if (kt & 1) { WRITE_A(aO, cur ^ 1); LOAD_A(aO, kt + 3); }
    else        { WRITE_A(aE, cur ^ 1); LOAD_A(aE, kt + 3); }
    COMPUTE(cur);
    SYNCV(4);                // drain own B(kt+1); A(kt+3) stays in flight
  }

  // ---- peeled tail: kt = 13, 14, 15 ----
  // kt=13 (cur=1): aO holds tile 14
  STAGE_B(14, 0);
  WRITE_A(aO, 0);
  COMPUTE(1);
  SYNCV(0);
  // kt=14 (cur=0): aE holds tile 15
  STAGE_B(15, 1);
  WRITE_A(aE, 1);
  COMPUTE(0);
  SYNCV(0);
  // kt=15 (cur=1)
  COMPUTE(1);

#undef LOAD_A
#undef WRITE_A
#undef STAGE_B
#undef COMPUTE

  // epilogue: C frag layout col=lane&15, row=(lane>>4)*4+j
#pragma unroll
  for (int c = 0; c < 3; ++c) {
    int gc = n0 + wid * 48 + c * 16 + lr;
    int mat = gc >> 7, h = gc & 127;
#pragma unroll
    for (int r = 0; r < 4; ++r) {
#pragma unroll
      for (int j = 0; j < 4; ++j) {
        int gr = m0 + r * 16 + lg * 4 + j;
        float val = acc[r][c][j];
        ushort ov = f2bf(mat == 0 ? val * QSCL : val);
        if (mat == 0) {
          qws[(size_t)gr * H_DIM + h] = ov;
        } else if (mat == 1) {
          kws[(size_t)gr * H_DIM + h] = ov;
        } else {
          int b = gr >> 11, t = gr & 2047;
          vtws[((size_t)b * H_DIM + h) * T_LEN + t] = ov;
        }
      }
    }
  }
}

// ---------------------------------------------------------------------------
// Kernel 2a: flash partial pass, block-cooperative LDS-staged K/V
// (unchanged from round 9).
// ---------------------------------------------------------------------------
__global__ __launch_bounds__(256, 3) void attn_part(const ushort* __restrict__ qws,
                                                    const ushort* __restrict__ kws,
                                                    const ushort* __restrict__ vtws,
                                                    float* __restrict__ pml,
                                                    ushort* __restrict__ pacc,
                                                    float* __restrict__ out) {
  __shared__ ushort Klds[64 * KSTR];
  __shared__ ushort Vlds[128 * VSTR];
  __shared__ ushort Pw[4][16 * PSTR];

  const int tid = threadIdx.x;
  const int wid = tid >> 6, lane = tid & 63;
  const int lg = lane >> 4, lr = lane & 15;
  const int bid = blockIdx.x;
  const int b = bid & 7;
  const int item = bid >> 3;

  int qb, ck;
  bool direct;
  if (item < 8) {
    qb = item; ck = 0; direct = true;
  } else {
    const int p = item - 8;
    direct = false;
    if (p < 12)      { int q = p / 3;        qb = 8 + q;  ck = p - q * 3; }
    else if (p < 28) { int q = (p - 12) >> 2; qb = 12 + q; ck = (p - 12) & 3; }
    else if (p < 48) { int q = (p - 28) / 5; qb = 16 + q; ck = (p - 28) - q * 5; }
    else if (p < 72) { int q = (p - 48) / 6; qb = 20 + q; ck = (p - 48) - q * 6; }
    else if (p < 100){ int q = (p - 72) / 7; qb = 24 + q; ck = (p - 72) - q * 7; }
    else             { int q = (p - 100) >> 3; qb = 28 + q; ck = (p - 100) & 7; }
  }
  const int qi = qb * 4 + wid;
  const int q0 = qi * 16;
  const int nt = qb + 1;
  const int kvt_lo = direct ? 0 : ck * 4;
  const int kvt_hi = direct ? nt : min(ck * 4 + 4, nt);
  const size_t tokbase = (size_t)b * T_LEN;
  const ushort* vb = vtws + (size_t)b * H_DIM * T_LEN;

  const int kr = tid >> 2, kseg = tid & 3;
  const int vr = tid >> 1, vseg = tid & 1;
  const ushort* gK = &kws[(tokbase + kr) * H_DIM + kseg * 32];
  const ushort* gV = &vb[(size_t)vr * T_LEN + vseg * 32];

  bf16x8 qf[4];
#pragma unroll
  for (int hk = 0; hk < 4; ++hk)
    qf[hk] = *(const bf16x8*)&qws[(tokbase + q0 + lr) * H_DIM + hk * 32 + lg * 8];

  f32x4 acc[8];
#pragma unroll
  for (int hf = 0; hf < 8; ++hf) acc[hf] = f32x4{0.f, 0.f, 0.f, 0.f};
  float mrun = -INFINITY, lrun = 0.f;

  ushort* Pme = &Pw[wid][0];

  us8 kreg[4], vreg[4];
#pragma unroll
  for (int i = 0; i < 4; ++i) {
    kreg[i] = *(const us8*)(gK + (size_t)kvt_lo * 64 * H_DIM + i * 8);
    vreg[i] = *(const us8*)(gV + kvt_lo * 64 + i * 8);
  }

  for (int kvt = kvt_lo; kvt < kvt_hi; ++kvt) {
    const int kv0 = kvt * 64;

    __syncthreads();
#pragma unroll
    for (int i = 0; i < 4; ++i) {
      *(us8*)&Klds[kr * KSTR + kseg * 32 + i * 8] = kreg[i];
      *(us8*)&Vlds[vr * VSTR + vseg * 32 + i * 8] = vreg[i];
    }
    if (kvt + 1 < kvt_hi) {
#pragma unroll
      for (int i = 0; i < 4; ++i) {
        kreg[i] = *(const us8*)(gK + (size_t)(kv0 + 64) * H_DIM + i * 8);
        vreg[i] = *(const us8*)(gV + kv0 + 64 + i * 8);
      }
    }
    __syncthreads();

    f32x4 s[4];
#pragma unroll
    for (int c = 0; c < 4; ++c) {
      f32x4 sc = f32x4{0.f, 0.f, 0.f, 0.f};
#pragma unroll
      for (int hk = 0; hk < 4; ++hk) {
        bf16x8 kf = *(const bf16x8*)&Klds[(c * 16 + lr) * KSTR + hk * 32 + lg * 8];
        sc = MFMA(kf, qf[hk], sc);
      }
      s[c] = sc;
    }

    if (kvt == nt - 1) {
#pragma unroll
      for (int c = 0; c < 4; ++c)
#pragma unroll
        for (int j = 0; j < 4; ++j) {
          int kv = kv0 + c * 16 + lg * 4 + j;
          if (kv > q0 + lr) s[c][j] = -INFINITY;
        }
    }

    float mx = s[0][0];
#pragma unroll
    for (int c = 0; c < 4; ++c)
#pragma unroll
      for (int j = 0; j < 4; ++j) mx = fmaxf(mx, s[c][j]);
    mx = fmaxf(mx, __shfl_xor(mx, 16));
    mx = fmaxf(mx, __shfl_xor(mx, 32));

    float mnew = fmaxf(mrun, mx);
    float scold = exp2f(mrun - mnew);

    float rsum = 0.f;
#pragma unroll
    for (int c = 0; c < 4; ++c)
#pragma unroll
      for (int j = 0; j < 4; ++j) {
        float p = exp2f(s[c][j] - mnew);
        s[c][j] = p;
        rsum += p;
      }

#pragma unroll
    for (int c = 0; c < 4; ++c) {
      ushort4 u;
      u.x = f2bf(s[c][0]); u.y = f2bf(s[c][1]);
      u.z = f2bf(s[c][2]); u.w = f2bf(s[c][3]);
      *(ushort4*)&Pme[lr * PSTR + c * 16 + lg * 4] = u;
    }

    bf16x8 v0[8];
#pragma unroll
    for (int hf = 0; hf < 8; ++hf)
      v0[hf] = *(const bf16x8*)&Vlds[(hf * 16 + lr) * VSTR + lg * 8];

    rsum += __shfl_xor(rsum, 16);
    rsum += __shfl_xor(rsum, 32);

    lrun = lrun * scold + rsum;
    mrun = mnew;
#pragma unroll
    for (int hf = 0; hf < 8; ++hf)
#pragma unroll
      for (int j = 0; j < 4; ++j) acc[hf][j] *= scold;

    bf16x8 pa0 = *(const bf16x8*)&Pme[lr * PSTR + lg * 8];
    bf16x8 pa1 = *(const bf16x8*)&Pme[lr * PSTR + 32 + lg * 8];

#pragma unroll
    for (int hf = 0; hf < 8; ++hf)
      acc[hf] = MFMA(v0[hf], pa0, acc[hf]);
#pragma unroll
    for (int hf = 0; hf < 8; ++hf) {
      bf16x8 v1 = *(const bf16x8*)&Vlds[(hf * 16 + lr) * VSTR + 32 + lg * 8];
      acc[hf] = MFMA(v1, pa1, acc[hf]);
    }
  }

  if (direct) {
    float inv = 1.0f / lrun;
    float* op = &out[(tokbase + q0 + lr) * H_DIM + lg * 4];
#pragma unroll
    for (int hf = 0; hf < 8; ++hf) {
      float4 r0 = make_float4(acc[hf][0] * inv, acc[hf][1] * inv,
                              acc[hf][2] * inv, acc[hf][3] * inv);
      *(float4*)(op + hf * 16) = r0;
    }
  } else {
    int base;
    if (qi < 48)       base = (qi - 32) * 3;
    else if (qi < 64)  base = 48 + (qi - 48) * 4;
    else if (qi < 80)  base = 112 + (qi - 64) * 5;
    else if (qi < 96)  base = 192 + (qi - 80) * 6;
    else if (qi < 112) base = 288 + (qi - 96) * 7;
    else               base = 400 + (qi - 112) * 8;
    const size_t slot = (size_t)b * SLOTS_PER_B + base + ck;
    if (lg == 0) {
      pml[slot * 32 + lr] = mrun;
      pml[slot * 32 + 16 + lr] = lrun;
    }
    ushort* ap = &pacc[slot * 2048 + (size_t)lr * 128 + lg * 4];
#pragma unroll
    for (int hf = 0; hf < 8; ++hf) {
      ushort4 u;
      u.x = f2bf(acc[hf][0]); u.y = f2bf(acc[hf][1]);
      u.z = f2bf(acc[hf][2]); u.w = f2bf(acc[hf][3]);
      *(ushort4*)(ap + hf * 16) = u;
    }
  }
}

// ---------------------------------------------------------------------------
// Kernel 2b: online merge of 3..8 partials per (b, qi) for qi >= 32.
// (unchanged)
// ---------------------------------------------------------------------------
__global__ __launch_bounds__(256) void attn_merge(const float* __restrict__ pml,
                                                  const ushort* __restrict__ pacc,
                                                  float* __restrict__ out) {
  const int bid = blockIdx.x;
  const int b = bid & 7, qi = (bid >> 3) + 32;
  int base, nch;
  if (qi < 48)       { base = (qi - 32) * 3;        nch = 3; }
  else if (qi < 64)  { base = 48 + (qi - 48) * 4;   nch = 4; }
  else if (qi < 80)  { base = 112 + (qi - 64) * 5;  nch = 5; }
  else if (qi < 96)  { base = 192 + (qi - 80) * 6;  nch = 6; }
  else if (qi < 112) { base = 288 + (qi - 96) * 7;  nch = 7; }
  else               { base = 400 + (qi - 112) * 8; nch = 8; }
  const size_t slot0 = (size_t)b * SLOTS_PER_B + base;
  const int tid = threadIdx.x;
  const int r = tid >> 4, c0 = (tid & 15) * 8;

  float mrun = -INFINITY, L = 0.f;
  float o[8];
#pragma unroll
  for (int i = 0; i < 8; ++i) o[i] = 0.f;

  for (int ck = 0; ck < nch; ++ck) {
    const size_t s = slot0 + ck;
    float m = pml[s * 32 + r];
    float l = pml[s * 32 + 16 + r];
    float mn = fmaxf(mrun, m);
    float sc = exp2f(mrun - mn);
    float w  = exp2f(m - mn);
    L = L * sc + w * l;
    const ushort* ap = &pacc[s * 2048 + (size_t)r * 128 + c0];
    ushort4 u0 = *(const ushort4*)ap;
    ushort4 u1 = *(const ushort4*)(ap + 4);
    o[0] = o[0] * sc + w * bf2f(u0.x); o[1] = o[1] * sc + w * bf2f(u0.y);
    o[2] = o[2] * sc + w * bf2f(u0.z); o[3] = o[3] * sc + w * bf2f(u0.w);
    o[4] = o[4] * sc + w * bf2f(u1.x); o[5] = o[5] * sc + w * bf2f(u1.y);
    o[6] = o[6] * sc + w * bf2f(u1.z); o[7] = o[7] * sc + w * bf2f(u1.w);
    mrun = mn;
  }
  float invL = 1.0f / L;
  float4 r0 = make_float4(o[0] * invL, o[1] * invL, o[2] * invL, o[3] * invL);
  float4 r1 = make_float4(o[4] * invL, o[5] * invL, o[6] * invL, o[7] * invL);
  float* op = &out[((size_t)b * T_LEN + qi * 16 + r) * H_DIM + c0];
  *(float4*)op = r0;
  *(float4*)(op + 4) = r1;
}

// ---------------------------------------------------------------------------
// ws layout identical to rounds 8-18 (total 30,670,848 B, proven fit):
//   [0, 786432) wt (dead after qkv_gemm; pml overlaps, 540,672 B)
//   qws / kws / vtws ; pacc = 8*528 slots * 2048 bf16
// ---------------------------------------------------------------------------
extern "C" void kernel_launch(void* const* d_in, const int* in_sizes, int n_in,
                              void* d_out, int out_size, void* d_ws, size_t ws_size,
                              hipStream_t stream) {
  const float* emb = (const float*)d_in[0];
  const float* Wq  = (const float*)d_in[1];
  const float* Wk  = (const float*)d_in[2];
  const float* Wv  = (const float*)d_in[3];
  float* out = (float*)d_out;

  ushort* wt   = (ushort*)d_ws;
  ushort* qws  = wt  + (size_t)N_COLS * C_DIM;
  ushort* kws  = qws + (size_t)M_ROWS * H_DIM;
  ushort* vtws = kws + (size_t)M_ROWS * H_DIM;
  ushort* pacc = vtws + (size_t)8 * H_DIM * T_LEN;
  float*  pml  = (float*)d_ws;   // overlaps dead wt region

  wt_convert<<<(N_COLS * C_DIM) / 256, 256, 0, stream>>>(Wq, Wk, Wv, wt);
  qkv_gemm<<<(M_ROWS / 64) * 2, 256, 0, stream>>>(emb, wt, qws, kws, vtws);
  attn_part<<<8 * 140, 256, 0, stream>>>(qws, kws, vtws, pml, pacc, out);
  attn_merge<<<8 * 96, 256, 0, stream>>>(pml, pacc, out);
}